// Round 1
// baseline (1661.800 us; speedup 1.0000x reference)
//
#include <hip/hip_runtime.h>

// db6 filter taps
#define D0  -0.00107730108499558f
#define D1   0.004777257511010651f
#define D2   0.0005538422009938016f
#define D3  -0.031582039318031156f
#define D4   0.02752286553001629f
#define D5   0.09750160558707936f
#define D6  -0.12976686756709563f
#define D7  -0.22626469396516913f
#define D8   0.3152503517092432f
#define D9   0.7511339080215775f
#define D10  0.4946238903983854f
#define D11  0.11154074335008017f

// a_lo = rec_lo = reversed(dec_lo); a_hi = dec_lo with odd idx negated
// s_lo = dec_lo; s_hi[i] = dec_lo[11-i] * (i even ? -1 : +1)
__constant__ float c_ALO[12] = { D11, D10, D9, D8, D7, D6, D5, D4, D3, D2, D1, D0 };
__constant__ float c_AHI[12] = { D0, -D1, D2, -D3, D4, -D5, D6, -D7, D8, -D9, D10, -D11 };
__constant__ float c_SLO[12] = { D0, D1, D2, D3, D4, D5, D6, D7, D8, D9, D10, D11 };
__constant__ float c_SHI[12] = { -D11, D10, -D9, D8, -D7, D6, -D5, D4, -D3, D2, -D1, D0 };

#define NB 512  // B*C = 8*64

// ---------------- DWT analysis ----------------

// Level-1 row pass, fused NCHW -> channel-last. x:[512,256,256] -> lo,hi:[256,133,512]
__global__ __launch_bounds__(256) void k_afb_rows_nchw(
    const float* __restrict__ x, float* __restrict__ lo, float* __restrict__ hi) {
  int blk = blockIdx.x;
  int h = blk / 133, k = blk - h * 133;
  int base = 2 * k - 10;
  long obase = ((long)h * 133 + k) * NB;
  for (int n = threadIdx.x; n < NB; n += 256) {
    const float* row = x + ((long)n * 256 + h) * 256;
    float aL = 0.f, aH = 0.f;
#pragma unroll
    for (int t = 0; t < 12; ++t) {
      int j = base + t;
      j = (j < 0) ? (-j - 1) : ((j >= 256) ? (511 - j) : j);
      float v = row[j];
      aL += v * c_ALO[t];
      aH += v * c_AHI[t];
    }
    lo[obase + n] = aL;
    hi[obase + n] = aH;
  }
}

// Row-analysis on channel-last [H, Win, 512] -> [H, outW, 512]
__global__ __launch_bounds__(256) void k_afb_rows_cl(
    const float* __restrict__ in, float* __restrict__ lo, float* __restrict__ hi,
    int Win, int outW, int padL) {
  int blk = blockIdx.x;
  int h = blk / outW, k = blk - h * outW;
  int base = 2 * k - padL;
  const float* rowb = in + (long)h * Win * NB;
  long obase = ((long)h * outW + k) * NB;
  for (int n = threadIdx.x; n < NB; n += 256) {
    float aL = 0.f, aH = 0.f;
#pragma unroll
    for (int t = 0; t < 12; ++t) {
      int j = base + t;
      j = (j < 0) ? (-j - 1) : ((j >= Win) ? (2 * Win - 1 - j) : j);
      float v = rowb[(long)j * NB + n];
      aL += v * c_ALO[t];
      aH += v * c_AHI[t];
    }
    lo[obase + n] = aL;
    hi[obase + n] = aH;
  }
}

// Column-analysis on channel-last [Hin, W, 512] -> [outH, W, 512]
__global__ __launch_bounds__(256) void k_afb_cols_cl(
    const float* __restrict__ in, float* __restrict__ lo, float* __restrict__ hi,
    int Hin, int W, int outH, int padL) {
  int blk = blockIdx.x;
  int k = blk / W, w = blk - k * W;
  int base = 2 * k - padL;
  long rstride = (long)W * NB;
  const float* colb = in + (long)w * NB;
  long obase = ((long)k * W + w) * NB;
  for (int n = threadIdx.x; n < NB; n += 256) {
    float aL = 0.f, aH = 0.f;
#pragma unroll
    for (int t = 0; t < 12; ++t) {
      int j = base + t;
      j = (j < 0) ? (-j - 1) : ((j >= Hin) ? (2 * Hin - 1 - j) : j);
      float v = colb[(long)j * rstride + n];
      aL += v * c_ALO[t];
      aH += v * c_AHI[t];
    }
    lo[obase + n] = aL;
    hi[obase + n] = aH;
  }
}

// ---------------- IDWT synthesis ----------------
// out[m] = sum_t u_pad[m+t]*S[t]; u is zero-upsampled (u[2j]=in[j]), pad 1 each side.
// contributing taps: t with (m+t-1) even, j=(m+t-1)/2 in [0,n)

// Column-synthesis: lo,hi (rows j, width W, CL) -> out [2n-10, W, 512] packed
__global__ __launch_bounds__(256) void k_sfb_cols_cl(
    const float* __restrict__ lo, long lors, const float* __restrict__ hi, long hirs,
    float* __restrict__ out, int n, int W, int outH) {
  int blk = blockIdx.x;
  int m = blk / W, w = blk - m * W;
  int t0 = 1 - (m & 1);
  const float* lob = lo + (long)w * NB;
  const float* hib = hi + (long)w * NB;
  long obase = ((long)m * W + w) * NB;
  for (int nn = threadIdx.x; nn < NB; nn += 256) {
    float acc = 0.f;
#pragma unroll
    for (int s6 = 0; s6 < 6; ++s6) {
      int t = t0 + 2 * s6;
      int j = (m + t - 1) >> 1;
      if (j >= 0 && j < n)
        acc += lob[(long)j * lors + nn] * c_SLO[t] + hib[(long)j * hirs + nn] * c_SHI[t];
    }
    out[obase + nn] = acc;
  }
}

// Row-synthesis: lo,hi [H, n, 512] (row stride given) -> out [H, 2n-10, 512] packed
__global__ __launch_bounds__(256) void k_sfb_rows_cl(
    const float* __restrict__ lo, long lors, const float* __restrict__ hi, long hirs,
    float* __restrict__ out, int n, int H, int outW) {
  int blk = blockIdx.x;
  int h = blk / outW, m = blk - h * outW;
  int t0 = 1 - (m & 1);
  const float* lob = lo + (long)h * lors;
  const float* hib = hi + (long)h * hirs;
  long obase = ((long)h * outW + m) * NB;
  for (int nn = threadIdx.x; nn < NB; nn += 256) {
    float acc = 0.f;
#pragma unroll
    for (int s6 = 0; s6 < 6; ++s6) {
      int t = t0 + 2 * s6;
      int j = (m + t - 1) >> 1;
      if (j >= 0 && j < n)
        acc += lob[(long)j * NB + nn] * c_SLO[t] + hib[(long)j * NB + nn] * c_SHI[t];
    }
    out[obase + nn] = acc;
  }
}

// Final level-1 row-synthesis fused with CL -> NCHW transpose.
// lo,hi: [256,133,512] -> out: [512,256,256]
__global__ __launch_bounds__(256) void k_sfb_rows_to_nchw(
    const float* __restrict__ lo, const float* __restrict__ hi, float* __restrict__ out) {
  __shared__ float lds[32 * 257];
  int h = blockIdx.x >> 3;
  int m0 = (blockIdx.x & 7) << 5;
  const float* lob = lo + (long)h * 133 * NB;
  const float* hib = hi + (long)h * 133 * NB;
  for (int c = 0; c < 2; ++c) {
    int n0 = c << 8;
    for (int idx = threadIdx.x; idx < 32 * 256; idx += 256) {
      int ml = idx >> 8, nl = idx & 255;
      int nn = n0 + nl;
      int m = m0 + ml;
      int t0 = 1 - (m & 1);
      float acc = 0.f;
#pragma unroll
      for (int s6 = 0; s6 < 6; ++s6) {
        int t = t0 + 2 * s6;
        int j = (m + t - 1) >> 1;
        if (j >= 0 && j < 133)
          acc += lob[(long)j * NB + nn] * c_SLO[t] + hib[(long)j * NB + nn] * c_SHI[t];
      }
      lds[ml * 257 + nl] = acc;
    }
    __syncthreads();
    for (int idx = threadIdx.x; idx < 32 * 256; idx += 256) {
      int nl = idx >> 5, ml = idx & 31;
      int nn = n0 + nl;
      out[((long)nn * 256 + h) * 256 + m0 + ml] = lds[ml * 257 + nl];
    }
    __syncthreads();
  }
}

// ---------------- weights ----------------

// W [io=4096, yx=4096] -> Wp [yx, io]
__global__ __launch_bounds__(256) void k_transpose_w(
    const float* __restrict__ in, float* __restrict__ out) {
  __shared__ float tile[32][33];
  int bx = blockIdx.x & 127, by = blockIdx.x >> 7;
  int x0 = bx * 32, y0 = by * 32;
  int tx = threadIdx.x & 31, ty = threadIdx.x >> 5;
  for (int r = ty; r < 32; r += 8)
    tile[r][tx] = in[(long)(y0 + r) * 4096 + x0 + tx];
  __syncthreads();
  for (int r = ty; r < 32; r += 8)
    out[(long)(x0 + r) * 4096 + y0 + tx] = tile[tx][r];
}

// ---------------- channel mix (einsum with bilinear-interp weights) ----------------
// One block per pixel. In-place on up to 4 subband arrays (channel-last, 512 contiguous).
__global__ __launch_bounds__(256) void k_mix(
    float* __restrict__ s0, float* __restrict__ s1, float* __restrict__ s2, float* __restrict__ s3,
    int nsub, const float* __restrict__ Wp, int Ho, int Wo) {
  __shared__ float Wm[4096];
  __shared__ float ins[NB];
  int p = blockIdx.x;
  int y = p / Wo, x = p - y * Wo;
  float sy = 64.0f / (float)Ho, sx = 64.0f / (float)Wo;
  float ys = fminf(fmaxf(((float)y + 0.5f) * sy - 0.5f, 0.0f), 63.0f);
  float xs = fminf(fmaxf(((float)x + 0.5f) * sx - 0.5f, 0.0f), 63.0f);
  int y0 = (int)ys, x0 = (int)xs;
  int y1 = min(y0 + 1, 63), x1 = min(x0 + 1, 63);
  float ty = ys - (float)y0, tx = xs - (float)x0;
  float w00 = (1.f - ty) * (1.f - tx), w01 = (1.f - ty) * tx;
  float w10 = ty * (1.f - tx), w11 = ty * tx;
  const float* p00 = Wp + (((long)y0 * 64 + x0) << 12);
  const float* p01 = Wp + (((long)y0 * 64 + x1) << 12);
  const float* p10 = Wp + (((long)y1 * 64 + x0) << 12);
  const float* p11 = Wp + (((long)y1 * 64 + x1) << 12);
  for (int t = threadIdx.x; t < 4096; t += 256)
    Wm[t] = w00 * p00[t] + w01 * p01[t] + w10 * p10[t] + w11 * p11[t];

  long pixoff = ((long)y * Wo + x) * NB;
  int bq = threadIdx.x >> 6;
  int o = threadIdx.x & 63;
  int b0 = bq * 2, b1 = b0 + 1;
  for (int s = 0; s < nsub; ++s) {
    float* base;
    if (s == 0) base = s0; else if (s == 1) base = s1; else if (s == 2) base = s2; else base = s3;
    base += pixoff;
    __syncthreads();  // Wm ready (s=0); previous iter's LDS reads done (s>0)
    for (int t = threadIdx.x; t < NB; t += 256) ins[t] = base[t];
    __syncthreads();
    float a0 = 0.f, a1 = 0.f;
#pragma unroll 16
    for (int i = 0; i < 64; ++i) {
      float w = Wm[(i << 6) + o];
      a0 += ins[(b0 << 6) + i] * w;
      a1 += ins[(b1 << 6) + i] * w;
    }
    base[(b0 << 6) + o] = a0;
    base[(b1 << 6) + o] = a1;
  }
}

// ---------------- driver ----------------

extern "C" void kernel_launch(void* const* d_in, const int* in_sizes, int n_in,
                              void* d_out, int out_size, void* d_ws, size_t ws_size,
                              hipStream_t stream) {
  const float* x = (const float*)d_in[0];
  const float* w = (const float*)d_in[1];
  float* out = (float*)d_out;
  float* ws = (float*)d_ws;

  // workspace layout (floats)
  float* T0  = ws;                 // 17,432,576 = 256*133*512  (also aliases WP)
  float* T1  = ws + 17432576;      // 17,432,576
  float* LL1 = ws + 34865152;      // cap 9,193,472 = 134*134*512 (recon2 reuse)
  float* LH1 = ws + 44058624;      // 9,056,768 each
  float* HL1 = ws + 53115392;
  float* HH1 = ws + 62172160;
  float* LL2 = ws + 71228928;      // 2,654,208 = 72*72*512
  float* LH2 = ws + 73883136;
  float* HL2 = ws + 76537344;
  float* HH2 = ws + 79191552;
  float* LL3 = ws + 81845760;      // 860,672 = 41*41*512
  float* LH3 = ws + 82706432;
  float* HL3 = ws + 83567104;
  float* HH3 = ws + 84427776;
  // total: 85,288,448 floats = 341.2 MB
  float* WP = T0;                  // weights [yx,io]; dead during idwt1 which reclaims T0

  dim3 blk(256);

  // DWT level 1 (256 -> 133)
  k_afb_rows_nchw<<<256 * 133, blk, 0, stream>>>(x, T0, T1);
  k_afb_cols_cl<<<133 * 133, blk, 0, stream>>>(T0, LL1, LH1, 256, 133, 133, 10);
  k_afb_cols_cl<<<133 * 133, blk, 0, stream>>>(T1, HL1, HH1, 256, 133, 133, 10);
  // level 2 (133 -> 72)
  k_afb_rows_cl<<<133 * 72, blk, 0, stream>>>(LL1, T0, T1, 133, 72, 10);
  k_afb_cols_cl<<<72 * 72, blk, 0, stream>>>(T0, LL2, LH2, 133, 72, 72, 10);
  k_afb_cols_cl<<<72 * 72, blk, 0, stream>>>(T1, HL2, HH2, 133, 72, 72, 10);
  // level 3 (72 -> 41)
  k_afb_rows_cl<<<72 * 41, blk, 0, stream>>>(LL2, T0, T1, 72, 41, 10);
  k_afb_cols_cl<<<41 * 41, blk, 0, stream>>>(T0, LL3, LH3, 72, 41, 41, 10);
  k_afb_cols_cl<<<41 * 41, blk, 0, stream>>>(T1, HL3, HH3, 72, 41, 41, 10);

  // weights transpose [io][yx] -> [yx][io]  (into T0, which is free until idwt1)
  k_transpose_w<<<128 * 128, blk, 0, stream>>>(w, WP);

  // channel mixes (in-place)
  k_mix<<<41 * 41, blk, 0, stream>>>(LL3, LH3, HL3, HH3, 4, WP, 41, 41);
  k_mix<<<72 * 72, blk, 0, stream>>>(LH2, HL2, HH2, nullptr, 3, WP, 72, 72);
  k_mix<<<133 * 133, blk, 0, stream>>>(LH1, HL1, HH1, nullptr, 3, WP, 133, 133);

  // IDWT level 3: (41 -> 72), temps in T1
  {
    float* C0 = T1;
    float* C1 = T1 + (long)72 * 41 * NB;  // 1,511,424
    k_sfb_cols_cl<<<72 * 41, blk, 0, stream>>>(LL3, (long)41 * NB, LH3, (long)41 * NB, C0, 41, 41, 72);
    k_sfb_cols_cl<<<72 * 41, blk, 0, stream>>>(HL3, (long)41 * NB, HH3, (long)41 * NB, C1, 41, 41, 72);
    k_sfb_rows_cl<<<72 * 72, blk, 0, stream>>>(C0, (long)41 * NB, C1, (long)41 * NB, LL2, 41, 72, 72);
  }
  // IDWT level 2: (72 -> 134), recon2 into LL1 buffer as [134,134,512]
  {
    float* C0 = T1;
    float* C1 = T1 + (long)134 * 72 * NB;  // 4,939,776
    k_sfb_cols_cl<<<134 * 72, blk, 0, stream>>>(LL2, (long)72 * NB, LH2, (long)72 * NB, C0, 72, 72, 134);
    k_sfb_cols_cl<<<134 * 72, blk, 0, stream>>>(HL2, (long)72 * NB, HH2, (long)72 * NB, C1, 72, 72, 134);
    k_sfb_rows_cl<<<134 * 134, blk, 0, stream>>>(C0, (long)72 * NB, C1, (long)72 * NB, LL1, 72, 134, 134);
  }
  // IDWT level 1: crop recon2 134->133 both dims; (133 -> 256); final fused to NCHW
  {
    k_sfb_cols_cl<<<256 * 133, blk, 0, stream>>>(LL1, (long)134 * NB, LH1, (long)133 * NB, T0, 133, 133, 256);
    k_sfb_cols_cl<<<256 * 133, blk, 0, stream>>>(HL1, (long)133 * NB, HH1, (long)133 * NB, T1, 133, 133, 256);
    k_sfb_rows_to_nchw<<<256 * 8, blk, 0, stream>>>(T0, T1, out);
  }
}